// Round 1
// baseline (382.539 us; speedup 1.0000x reference)
//
#include <hip/hip_runtime.h>
#include <hip/hip_bf16.h>

typedef __bf16 bf16x8 __attribute__((ext_vector_type(8)));
typedef float f32x4 __attribute__((ext_vector_type(4)));
typedef unsigned short u16x8 __attribute__((ext_vector_type(8)));

__device__ inline unsigned short f2bf(float f) {
  __hip_bfloat16 h = __float2bfloat16(f);
  return __builtin_bit_cast(unsigned short, h);
}

__device__ inline f32x4 zero4() {
  f32x4 z;
  #pragma unroll
  for (int i = 0; i < 4; ++i) z[i] = 0.0f;
  return z;
}

// ---------------- cast x: fp32 -> bf16 ----------------
__global__ __launch_bounds__(256) void cast_x_kernel(const float* __restrict__ in,
                                                     unsigned short* __restrict__ out, int n4) {
  int i = blockIdx.x * 256 + threadIdx.x;
  if (i < n4) {
    float4 v = ((const float4*)in)[i];
    ushort4 o;
    o.x = f2bf(v.x); o.y = f2bf(v.y); o.z = f2bf(v.z); o.w = f2bf(v.w);
    ((ushort4*)out)[i] = o;
  }
}

// ---------------- transpose + cast: W[R][C] fp32 -> WT[C][R] bf16 ----------------
__global__ __launch_bounds__(256) void transpose_cast_kernel(const float* __restrict__ in,
                                                             unsigned short* __restrict__ out,
                                                             int R, int C) {
  __shared__ float tile[32][33];
  int c0 = blockIdx.x * 32, r0 = blockIdx.y * 32;
  int tx = threadIdx.x, ty = threadIdx.y;  // (32,8)
  #pragma unroll
  for (int i = 0; i < 4; i++)
    tile[ty + i * 8][tx] = in[(size_t)(r0 + ty + i * 8) * C + c0 + tx];
  __syncthreads();
  #pragma unroll
  for (int i = 0; i < 4; i++)
    out[(size_t)(c0 + ty + i * 8) * R + r0 + tx] = f2bf(tile[tx][ty + i * 8]);
}

// ---------------- shared GEMM mainloop: C[128x128] tile = A[M,K] @ BT[N,K]^T ----------------
// 256 threads = 4 waves (2x2 of 64x64). LDS rows padded to 72 elems (144B) for b128 reads.
template <int KDIM>
__device__ inline void gemm_tile(const unsigned short* __restrict__ A,
                                 const unsigned short* __restrict__ BT,
                                 int m0, int n0,
                                 unsigned short* ldsA, unsigned short* ldsB,
                                 f32x4 acc[4][4]) {
  const int t = threadIdx.x;
  const int lane = t & 63;
  const int w = t >> 6;
  const int wm = w >> 1, wn = w & 1;
  const int fr = lane & 15;
  const int fg = lane >> 4;

  #pragma unroll
  for (int m = 0; m < 4; m++)
    #pragma unroll
    for (int n = 0; n < 4; n++) acc[m][n] = zero4();

  for (int kt = 0; kt < KDIM / 64; ++kt) {
    #pragma unroll
    for (int p = 0; p < 4; p++) {
      int c = t + p * 256;
      int row = c >> 3, cc = c & 7;
      *(u16x8*)(ldsA + row * 72 + cc * 8) =
          *(const u16x8*)(A + (size_t)(m0 + row) * KDIM + kt * 64 + cc * 8);
      *(u16x8*)(ldsB + row * 72 + cc * 8) =
          *(const u16x8*)(BT + (size_t)(n0 + row) * KDIM + kt * 64 + cc * 8);
    }
    __syncthreads();
    #pragma unroll
    for (int ks = 0; ks < 2; ++ks) {
      bf16x8 a[4], b[4];
      #pragma unroll
      for (int m = 0; m < 4; m++)
        a[m] = *(const bf16x8*)(ldsA + (wm * 64 + m * 16 + fr) * 72 + ks * 32 + fg * 8);
      #pragma unroll
      for (int n = 0; n < 4; n++)
        b[n] = *(const bf16x8*)(ldsB + (wn * 64 + n * 16 + fr) * 72 + ks * 32 + fg * 8);
      #pragma unroll
      for (int m = 0; m < 4; m++)
        #pragma unroll
        for (int n = 0; n < 4; n++)
          acc[m][n] = __builtin_amdgcn_mfma_f32_16x16x32_bf16(a[m], b[n], acc[m][n], 0, 0, 0);
    }
    __syncthreads();
  }
}

// ---------------- GEMM1: x@Wqkv + b, scatter to Q(scaled)/K/V [B,H,N,64] bf16 ----------------
__global__ __launch_bounds__(256) void gemm_qkv_kernel(const unsigned short* __restrict__ xbf,
                                                       const unsigned short* __restrict__ WqkvT,
                                                       const float* __restrict__ bqkv,
                                                       unsigned short* __restrict__ Qws,
                                                       unsigned short* __restrict__ Kws,
                                                       unsigned short* __restrict__ Vws) {
  __shared__ unsigned short ldsA[128 * 72];
  __shared__ unsigned short ldsB[128 * 72];
  int m0 = blockIdx.y * 128, n0 = blockIdx.x * 128;
  f32x4 acc[4][4];
  gemm_tile<1024>(xbf, WqkvT, m0, n0, ldsA, ldsB, acc);

  const int lane = threadIdx.x & 63;
  const int w = threadIdx.x >> 6;
  const int wm = w >> 1, wn = w & 1;
  const int fr = lane & 15, fg = lane >> 4;
  #pragma unroll
  for (int m = 0; m < 4; m++) {
    #pragma unroll
    for (int n = 0; n < 4; n++) {
      int col = n0 + wn * 64 + n * 16 + fr;
      int s = col >> 10, h = (col >> 6) & 15, d = col & 63;
      float bias = bqkv[col];
      float sc = (s == 0) ? 0.125f : 1.0f;  // fold SCALE=1/8 into Q (exact)
      unsigned short* dst = (s == 0) ? Qws : ((s == 1) ? Kws : Vws);
      #pragma unroll
      for (int r = 0; r < 4; r++) {
        int row = m0 + wm * 64 + m * 16 + fg * 4 + r;
        int bb = row >> 11, tok = row & 2047;
        dst[((size_t)(bb * 16 + h) * 2048 + tok) * 64 + d] = f2bf((acc[m][n][r] + bias) * sc);
      }
    }
  }
}

// ---------------- flash attention: block = (b,h, 64 q rows), 4 waves x 16 q rows ----------------
__global__ __launch_bounds__(256) void attn_kernel(const unsigned short* __restrict__ Qws,
                                                   const unsigned short* __restrict__ Kws,
                                                   const unsigned short* __restrict__ Vws,
                                                   unsigned short* __restrict__ attn_out) {
  __shared__ unsigned short ldsK[64 * 72];
  __shared__ unsigned short ldsV[64 * 72];
  const int t = threadIdx.x, lane = t & 63, w = t >> 6;
  const int bh = blockIdx.x >> 5, qt = blockIdx.x & 31;
  const int q0 = qt * 64;
  const int fr = lane & 15, fg = lane >> 4;
  const int q = q0 + w * 16 + fr;
  const size_t bhbase = (size_t)bh * 2048;

  // Q fragments (Q already pre-scaled by 1/8): lane holds Q[q][d=(fg*8..)+{0,32}]
  const unsigned short* qrow = Qws + (bhbase + q) * 64;
  bf16x8 qf0 = *(const bf16x8*)(qrow + fg * 8);
  bf16x8 qf1 = *(const bf16x8*)(qrow + 32 + fg * 8);

  float m_run = -1e30f, l_run = 0.0f;
  f32x4 ot[4];
  #pragma unroll
  for (int dt = 0; dt < 4; dt++) ot[dt] = zero4();

  for (int kb = 0; kb < 2048; kb += 64) {
    // stage K,V tiles [64][64] (padded rows 72)
    #pragma unroll
    for (int p = 0; p < 2; p++) {
      int c = t + p * 256;
      int row = c >> 3, cc = c & 7;
      *(u16x8*)(ldsK + row * 72 + cc * 8) =
          *(const u16x8*)(Kws + (bhbase + kb + row) * 64 + cc * 8);
      *(u16x8*)(ldsV + row * 72 + cc * 8) =
          *(const u16x8*)(Vws + (bhbase + kb + row) * 64 + cc * 8);
    }
    __syncthreads();

    // S^T[key][q] = K_tile @ Q^T  (so per-lane q = fr, keys = fg*4+r over 4 chunks)
    f32x4 st[4];
    #pragma unroll
    for (int kc = 0; kc < 4; kc++) {
      st[kc] = zero4();
      bf16x8 a0 = *(const bf16x8*)(ldsK + (kc * 16 + fr) * 72 + fg * 8);
      bf16x8 a1 = *(const bf16x8*)(ldsK + (kc * 16 + fr) * 72 + 32 + fg * 8);
      st[kc] = __builtin_amdgcn_mfma_f32_16x16x32_bf16(a0, qf0, st[kc], 0, 0, 0);
      st[kc] = __builtin_amdgcn_mfma_f32_16x16x32_bf16(a1, qf1, st[kc], 0, 0, 0);
    }

    // online softmax (state replicated across the 4 lane-groups)
    float tmax = -1e30f;
    #pragma unroll
    for (int kc = 0; kc < 4; kc++)
      #pragma unroll
      for (int r = 0; r < 4; r++) tmax = fmaxf(tmax, st[kc][r]);
    tmax = fmaxf(tmax, __shfl_xor(tmax, 16, 64));
    tmax = fmaxf(tmax, __shfl_xor(tmax, 32, 64));
    float m_new = fmaxf(m_run, tmax);
    float corr = __expf(m_run - m_new);
    float tsum = 0.0f;
    #pragma unroll
    for (int kc = 0; kc < 4; kc++)
      #pragma unroll
      for (int r = 0; r < 4; r++) {
        st[kc][r] = __expf(st[kc][r] - m_new);
        tsum += st[kc][r];
      }
    tsum += __shfl_xor(tsum, 16, 64);
    tsum += __shfl_xor(tsum, 32, 64);
    l_run = l_run * corr + tsum;
    m_run = m_new;
    #pragma unroll
    for (int dt = 0; dt < 4; dt++) ot[dt] *= corr;

    // P^T -> bf16 B-frags (j=0..3 real keys, 4..7 zero-padded)
    u16x8 pb[4];
    #pragma unroll
    for (int kc = 0; kc < 4; kc++) {
      u16x8 v;
      #pragma unroll
      for (int j = 0; j < 8; j++) v[j] = 0;
      #pragma unroll
      for (int j = 0; j < 4; j++) v[j] = f2bf(st[kc][j]);
      pb[kc] = v;
    }

    // O^T[d][q] += V^T @ P^T via padded 16x16x32 (A j=0..3 real V, j=4..7 zero)
    #pragma unroll
    for (int dt = 0; dt < 4; dt++) {
      #pragma unroll
      for (int kc = 0; kc < 4; kc++) {
        u16x8 av;
        #pragma unroll
        for (int j = 0; j < 8; j++) av[j] = 0;
        #pragma unroll
        for (int j = 0; j < 4; j++)
          av[j] = ldsV[(kc * 16 + fg * 4 + j) * 72 + dt * 16 + fr];
        ot[dt] = __builtin_amdgcn_mfma_f32_16x16x32_bf16(
            __builtin_bit_cast(bf16x8, av), __builtin_bit_cast(bf16x8, pb[kc]), ot[dt], 0, 0, 0);
      }
    }
    __syncthreads();
  }

  float rl = 1.0f / l_run;
  int b = bh >> 4, h = bh & 15;
  #pragma unroll
  for (int dt = 0; dt < 4; dt++) {
    ushort4 o;
    o.x = f2bf(ot[dt][0] * rl);
    o.y = f2bf(ot[dt][1] * rl);
    o.z = f2bf(ot[dt][2] * rl);
    o.w = f2bf(ot[dt][3] * rl);
    int d = dt * 16 + fg * 4;
    *(ushort4*)(attn_out + ((size_t)b * 2048 + q) * 1024 + h * 64 + d) = o;
  }
}

// ---------------- GEMM2: attn_out @ Wout + b -> fp32 out ----------------
__global__ __launch_bounds__(256) void gemm_out_kernel(const unsigned short* __restrict__ attn,
                                                       const unsigned short* __restrict__ WoutT,
                                                       const float* __restrict__ bout,
                                                       float* __restrict__ out) {
  __shared__ unsigned short ldsA[128 * 72];
  __shared__ unsigned short ldsB[128 * 72];
  int m0 = blockIdx.y * 128, n0 = blockIdx.x * 128;
  f32x4 acc[4][4];
  gemm_tile<1024>(attn, WoutT, m0, n0, ldsA, ldsB, acc);

  const int lane = threadIdx.x & 63;
  const int w = threadIdx.x >> 6;
  const int wm = w >> 1, wn = w & 1;
  const int fr = lane & 15, fg = lane >> 4;
  #pragma unroll
  for (int m = 0; m < 4; m++) {
    #pragma unroll
    for (int n = 0; n < 4; n++) {
      int col = n0 + wn * 64 + n * 16 + fr;
      float bias = bout[col];
      #pragma unroll
      for (int r = 0; r < 4; r++) {
        int row = m0 + wm * 64 + m * 16 + fg * 4 + r;
        out[(size_t)row * 1024 + col] = acc[m][n][r] + bias;
      }
    }
  }
}

extern "C" void kernel_launch(void* const* d_in, const int* in_sizes, int n_in,
                              void* d_out, int out_size, void* d_ws, size_t ws_size,
                              hipStream_t stream) {
  const float* x = (const float*)d_in[0];
  const float* Wqkv = (const float*)d_in[1];
  const float* bqkv = (const float*)d_in[2];
  const float* Wout = (const float*)d_in[3];
  const float* bout = (const float*)d_in[4];
  float* out = (float*)d_out;

  unsigned short* xbf = (unsigned short*)d_ws;        // 8192*1024
  unsigned short* wqkvT = xbf + 8388608;              // 3072*1024
  unsigned short* woutT = wqkvT + 3145728;            // 1024*1024
  unsigned short* Qws = woutT + 1048576;              // 64*2048*64
  unsigned short* Kws = Qws + 8388608;
  unsigned short* Vws = Kws + 8388608;
  unsigned short* attn = Vws + 8388608;               // 8192*1024
  // total ws use: 92,274,688 bytes

  cast_x_kernel<<<2097152 / 256, 256, 0, stream>>>(x, xbf, 2097152);
  transpose_cast_kernel<<<dim3(96, 32), dim3(32, 8), 0, stream>>>(Wqkv, wqkvT, 1024, 3072);
  transpose_cast_kernel<<<dim3(32, 32), dim3(32, 8), 0, stream>>>(Wout, woutT, 1024, 1024);
  gemm_qkv_kernel<<<dim3(24, 64), 256, 0, stream>>>(xbf, wqkvT, bqkv, Qws, Kws, Vws);
  attn_kernel<<<2048, 256, 0, stream>>>(Qws, Kws, Vws, attn);
  gemm_out_kernel<<<dim3(8, 64), 256, 0, stream>>>(attn, woutT, bout, out);
}

// Round 2
// 324.838 us; speedup vs baseline: 1.1776x; 1.1776x over previous
//
#include <hip/hip_runtime.h>
#include <hip/hip_bf16.h>

typedef __bf16 bf16x8 __attribute__((ext_vector_type(8)));
typedef float f32x4 __attribute__((ext_vector_type(4)));
typedef unsigned short u16x8 __attribute__((ext_vector_type(8)));

__device__ inline unsigned short f2bf(float f) {
  __hip_bfloat16 h = __float2bfloat16(f);
  return __builtin_bit_cast(unsigned short, h);
}

__device__ inline f32x4 zero4() {
  f32x4 z;
  #pragma unroll
  for (int i = 0; i < 4; ++i) z[i] = 0.0f;
  return z;
}

// ---------------- cast x: fp32 -> bf16 ----------------
__global__ __launch_bounds__(256) void cast_x_kernel(const float* __restrict__ in,
                                                     unsigned short* __restrict__ out, int n4) {
  int i = blockIdx.x * 256 + threadIdx.x;
  if (i < n4) {
    float4 v = ((const float4*)in)[i];
    ushort4 o;
    o.x = f2bf(v.x); o.y = f2bf(v.y); o.z = f2bf(v.z); o.w = f2bf(v.w);
    ((ushort4*)out)[i] = o;
  }
}

// ---------------- transpose + cast: W[R][C] fp32 -> WT[C][R] bf16 ----------------
__global__ __launch_bounds__(256) void transpose_cast_kernel(const float* __restrict__ in,
                                                             unsigned short* __restrict__ out,
                                                             int R, int C) {
  __shared__ float tile[32][33];
  int c0 = blockIdx.x * 32, r0 = blockIdx.y * 32;
  int tx = threadIdx.x, ty = threadIdx.y;  // (32,8)
  #pragma unroll
  for (int i = 0; i < 4; i++)
    tile[ty + i * 8][tx] = in[(size_t)(r0 + ty + i * 8) * C + c0 + tx];
  __syncthreads();
  #pragma unroll
  for (int i = 0; i < 4; i++)
    out[(size_t)(c0 + ty + i * 8) * R + r0 + tx] = f2bf(tile[tx][ty + i * 8]);
}

// ---------------- transpose V: [bh][2048 tok][64 d] bf16 -> Vt [bh][64 d][2048 tok] ----------------
__global__ __launch_bounds__(256) void transpose_v_kernel(const unsigned short* __restrict__ V,
                                                          unsigned short* __restrict__ Vt) {
  __shared__ unsigned short tile[32][33];
  int k0 = blockIdx.x * 32, d0 = blockIdx.y * 32, bh = blockIdx.z;
  int tx = threadIdx.x, ty = threadIdx.y;  // (32,8)
  #pragma unroll
  for (int i = 0; i < 4; i++)
    tile[ty + i * 8][tx] = V[((size_t)bh * 2048 + k0 + ty + i * 8) * 64 + d0 + tx];
  __syncthreads();
  #pragma unroll
  for (int i = 0; i < 4; i++)
    Vt[((size_t)bh * 64 + d0 + ty + i * 8) * 2048 + k0 + tx] = tile[tx][ty + i * 8];
}

// ---------------- shared GEMM mainloop: C[128x128] tile = A[M,K] @ BT[N,K]^T ----------------
template <int KDIM>
__device__ inline void gemm_tile(const unsigned short* __restrict__ A,
                                 const unsigned short* __restrict__ BT,
                                 int m0, int n0,
                                 unsigned short* ldsA, unsigned short* ldsB,
                                 f32x4 acc[4][4]) {
  const int t = threadIdx.x;
  const int lane = t & 63;
  const int w = t >> 6;
  const int wm = w >> 1, wn = w & 1;
  const int fr = lane & 15;
  const int fg = lane >> 4;

  #pragma unroll
  for (int m = 0; m < 4; m++)
    #pragma unroll
    for (int n = 0; n < 4; n++) acc[m][n] = zero4();

  for (int kt = 0; kt < KDIM / 64; ++kt) {
    #pragma unroll
    for (int p = 0; p < 4; p++) {
      int c = t + p * 256;
      int row = c >> 3, cc = c & 7;
      *(u16x8*)(ldsA + row * 72 + cc * 8) =
          *(const u16x8*)(A + (size_t)(m0 + row) * KDIM + kt * 64 + cc * 8);
      *(u16x8*)(ldsB + row * 72 + cc * 8) =
          *(const u16x8*)(BT + (size_t)(n0 + row) * KDIM + kt * 64 + cc * 8);
    }
    __syncthreads();
    #pragma unroll
    for (int ks = 0; ks < 2; ++ks) {
      bf16x8 a[4], b[4];
      #pragma unroll
      for (int m = 0; m < 4; m++)
        a[m] = *(const bf16x8*)(ldsA + (wm * 64 + m * 16 + fr) * 72 + ks * 32 + fg * 8);
      #pragma unroll
      for (int n = 0; n < 4; n++)
        b[n] = *(const bf16x8*)(ldsB + (wn * 64 + n * 16 + fr) * 72 + ks * 32 + fg * 8);
      #pragma unroll
      for (int m = 0; m < 4; m++)
        #pragma unroll
        for (int n = 0; n < 4; n++)
          acc[m][n] = __builtin_amdgcn_mfma_f32_16x16x32_bf16(a[m], b[n], acc[m][n], 0, 0, 0);
    }
    __syncthreads();
  }
}

// ---------------- GEMM1: x@Wqkv + b, scatter to Q(scaled)/K/V [B,H,N,64] bf16 ----------------
__global__ __launch_bounds__(256) void gemm_qkv_kernel(const unsigned short* __restrict__ xbf,
                                                       const unsigned short* __restrict__ WqkvT,
                                                       const float* __restrict__ bqkv,
                                                       unsigned short* __restrict__ Qws,
                                                       unsigned short* __restrict__ Kws,
                                                       unsigned short* __restrict__ Vws) {
  __shared__ unsigned short ldsA[128 * 72];
  __shared__ unsigned short ldsB[128 * 72];
  int m0 = blockIdx.y * 128, n0 = blockIdx.x * 128;
  f32x4 acc[4][4];
  gemm_tile<1024>(xbf, WqkvT, m0, n0, ldsA, ldsB, acc);

  const int lane = threadIdx.x & 63;
  const int w = threadIdx.x >> 6;
  const int wm = w >> 1, wn = w & 1;
  const int fr = lane & 15, fg = lane >> 4;
  #pragma unroll
  for (int m = 0; m < 4; m++) {
    #pragma unroll
    for (int n = 0; n < 4; n++) {
      int col = n0 + wn * 64 + n * 16 + fr;
      int s = col >> 10, h = (col >> 6) & 15, d = col & 63;
      float bias = bqkv[col];
      float sc = (s == 0) ? 0.125f : 1.0f;  // fold SCALE=1/8 into Q (exact)
      unsigned short* dst = (s == 0) ? Qws : ((s == 1) ? Kws : Vws);
      #pragma unroll
      for (int r = 0; r < 4; r++) {
        int row = m0 + wm * 64 + m * 16 + fg * 4 + r;
        int bb = row >> 11, tok = row & 2047;
        dst[((size_t)(bb * 16 + h) * 2048 + tok) * 64 + d] = f2bf((acc[m][n][r] + bias) * sc);
      }
    }
  }
}

// ---------------- flash attention v2 ----------------
// block = (b,h, 128 q rows), 4 waves x 32 q rows (2 q-frags of 16).
// Key permutation: K row `kk` staged at LDS slot sigma(kk) so that QK^T chunk c reads
// contiguous slots c*16+fr and the output registers directly form PV's B-fragment:
//   st[u][c] reg r at lane(fr,fg) holds key (c>>1)*32 + fg*8 + (c&1)*4 + r, q = fr.
// PV: O^T[d][q] = sum_k Vt[d][k] * P^T[k][q]; A-frag = ds_read_b128 of Vt row d.
__global__ __launch_bounds__(256) void attn_kernel(const unsigned short* __restrict__ Qws,
                                                   const unsigned short* __restrict__ Kws,
                                                   const unsigned short* __restrict__ Vtws,
                                                   unsigned short* __restrict__ attn_out) {
  __shared__ unsigned short ldsK[64 * 72];
  __shared__ unsigned short ldsV[64 * 72];
  const int t = threadIdx.x, lane = t & 63, w = t >> 6;
  const int bh = blockIdx.x >> 4, qt = blockIdx.x & 15;
  const int q0 = qt * 128;
  const int fr = lane & 15, fg = lane >> 4;
  const size_t bhbase = (size_t)bh * 2048;

  // Q fragments (pre-scaled by 1/8): u=0,1 -> q = q0 + w*32 + u*16 + fr
  bf16x8 qf[2][2];
  #pragma unroll
  for (int u = 0; u < 2; u++) {
    const unsigned short* qrow = Qws + (bhbase + q0 + w * 32 + u * 16 + fr) * 64;
    qf[u][0] = *(const bf16x8*)(qrow + fg * 8);
    qf[u][1] = *(const bf16x8*)(qrow + 32 + fg * 8);
  }

  float m_run[2] = {-1e30f, -1e30f}, l_run[2] = {0.0f, 0.0f};
  f32x4 ot[2][4];
  #pragma unroll
  for (int u = 0; u < 2; u++)
    #pragma unroll
    for (int dt = 0; dt < 4; dt++) ot[u][dt] = zero4();

  // staging decomposition: c = t + p*256; row = c>>3 (0..63), cc = c&7
  int kslot[2];
  #pragma unroll
  for (int p = 0; p < 2; p++) {
    int kk = (t + p * 256) >> 3;
    int w32 = kk & 31;
    kslot[p] = ((kk >> 5) * 2 + ((w32 >> 2) & 1)) * 16 + ((w32 >> 3) << 2) + (w32 & 3);
  }

  for (int kb = 0; kb < 2048; kb += 64) {
    // global -> regs (latency overlaps the barrier)
    u16x8 kreg[2], vreg[2];
    #pragma unroll
    for (int p = 0; p < 2; p++) {
      int c = t + p * 256;
      int row = c >> 3, cc = c & 7;
      kreg[p] = *(const u16x8*)(Kws + (bhbase + kb + row) * 64 + cc * 8);
      vreg[p] = *(const u16x8*)(Vtws + ((size_t)bh * 64 + row) * 2048 + kb + cc * 8);
    }
    __syncthreads();  // previous tile fully consumed
    #pragma unroll
    for (int p = 0; p < 2; p++) {
      int c = t + p * 256;
      int row = c >> 3, cc = c & 7;
      *(u16x8*)(ldsK + kslot[p] * 72 + cc * 8) = kreg[p];
      *(u16x8*)(ldsV + row * 72 + cc * 8) = vreg[p];
    }
    __syncthreads();

    // QK^T: S^T chunks (permuted key order)
    f32x4 st[2][4];
    #pragma unroll
    for (int c = 0; c < 4; c++) {
      bf16x8 a0 = *(const bf16x8*)(ldsK + (c * 16 + fr) * 72 + fg * 8);
      bf16x8 a1 = *(const bf16x8*)(ldsK + (c * 16 + fr) * 72 + 32 + fg * 8);
      #pragma unroll
      for (int u = 0; u < 2; u++) {
        st[u][c] = __builtin_amdgcn_mfma_f32_16x16x32_bf16(a0, qf[u][0], zero4(), 0, 0, 0);
        st[u][c] = __builtin_amdgcn_mfma_f32_16x16x32_bf16(a1, qf[u][1], st[u][c], 0, 0, 0);
      }
    }

    // online softmax (per q-frag; state replicated across 4 fg groups)
    u16x8 pb[2][2];
    #pragma unroll
    for (int u = 0; u < 2; u++) {
      float tmax = -1e30f;
      #pragma unroll
      for (int c = 0; c < 4; c++)
        #pragma unroll
        for (int r = 0; r < 4; r++) tmax = fmaxf(tmax, st[u][c][r]);
      tmax = fmaxf(tmax, __shfl_xor(tmax, 16, 64));
      tmax = fmaxf(tmax, __shfl_xor(tmax, 32, 64));
      float m_new = fmaxf(m_run[u], tmax);
      float corr = __expf(m_run[u] - m_new);
      float tsum = 0.0f;
      #pragma unroll
      for (int c = 0; c < 4; c++)
        #pragma unroll
        for (int r = 0; r < 4; r++) {
          st[u][c][r] = __expf(st[u][c][r] - m_new);
          tsum += st[u][c][r];
        }
      tsum += __shfl_xor(tsum, 16, 64);
      tsum += __shfl_xor(tsum, 32, 64);
      l_run[u] = l_run[u] * corr + tsum;
      m_run[u] = m_new;
      #pragma unroll
      for (int dt = 0; dt < 4; dt++) ot[u][dt] *= corr;

      // P -> bf16 B-frags: pb[kc] = {st[2kc][0..3], st[2kc+1][0..3]} (all 8 lanes real)
      #pragma unroll
      for (int kc = 0; kc < 2; kc++) {
        u16x8 v;
        #pragma unroll
        for (int j = 0; j < 4; j++) {
          v[j] = f2bf(st[u][kc * 2][j]);
          v[4 + j] = f2bf(st[u][kc * 2 + 1][j]);
        }
        pb[u][kc] = v;
      }
    }

    // PV: O^T[d][q] += Vt-chunk @ P^T (full K=32, vector A reads)
    #pragma unroll
    for (int dt = 0; dt < 4; dt++) {
      #pragma unroll
      for (int kc = 0; kc < 2; kc++) {
        bf16x8 av = *(const bf16x8*)(ldsV + (dt * 16 + fr) * 72 + kc * 32 + fg * 8);
        #pragma unroll
        for (int u = 0; u < 2; u++)
          ot[u][dt] = __builtin_amdgcn_mfma_f32_16x16x32_bf16(
              av, __builtin_bit_cast(bf16x8, pb[u][kc]), ot[u][dt], 0, 0, 0);
      }
    }
  }

  const int b = bh >> 4, h = bh & 15;
  #pragma unroll
  for (int u = 0; u < 2; u++) {
    float rl = 1.0f / l_run[u];
    int q = q0 + w * 32 + u * 16 + fr;
    #pragma unroll
    for (int dt = 0; dt < 4; dt++) {
      ushort4 o;
      o.x = f2bf(ot[u][dt][0] * rl);
      o.y = f2bf(ot[u][dt][1] * rl);
      o.z = f2bf(ot[u][dt][2] * rl);
      o.w = f2bf(ot[u][dt][3] * rl);
      int d = dt * 16 + fg * 4;
      *(ushort4*)(attn_out + ((size_t)b * 2048 + q) * 1024 + h * 64 + d) = o;
    }
  }
}

// ---------------- GEMM2: attn_out @ Wout + b -> fp32 out ----------------
__global__ __launch_bounds__(256) void gemm_out_kernel(const unsigned short* __restrict__ attn,
                                                       const unsigned short* __restrict__ WoutT,
                                                       const float* __restrict__ bout,
                                                       float* __restrict__ out) {
  __shared__ unsigned short ldsA[128 * 72];
  __shared__ unsigned short ldsB[128 * 72];
  int m0 = blockIdx.y * 128, n0 = blockIdx.x * 128;
  f32x4 acc[4][4];
  gemm_tile<1024>(attn, WoutT, m0, n0, ldsA, ldsB, acc);

  const int lane = threadIdx.x & 63;
  const int w = threadIdx.x >> 6;
  const int wm = w >> 1, wn = w & 1;
  const int fr = lane & 15, fg = lane >> 4;
  #pragma unroll
  for (int m = 0; m < 4; m++) {
    #pragma unroll
    for (int n = 0; n < 4; n++) {
      int col = n0 + wn * 64 + n * 16 + fr;
      float bias = bout[col];
      #pragma unroll
      for (int r = 0; r < 4; r++) {
        int row = m0 + wm * 64 + m * 16 + fg * 4 + r;
        out[(size_t)row * 1024 + col] = acc[m][n][r] + bias;
      }
    }
  }
}

extern "C" void kernel_launch(void* const* d_in, const int* in_sizes, int n_in,
                              void* d_out, int out_size, void* d_ws, size_t ws_size,
                              hipStream_t stream) {
  const float* x = (const float*)d_in[0];
  const float* Wqkv = (const float*)d_in[1];
  const float* bqkv = (const float*)d_in[2];
  const float* Wout = (const float*)d_in[3];
  const float* bout = (const float*)d_in[4];
  float* out = (float*)d_out;

  unsigned short* xbf = (unsigned short*)d_ws;        // 8192*1024 (aliased as attn buffer later)
  unsigned short* wqkvT = xbf + 8388608;              // 3072*1024
  unsigned short* woutT = wqkvT + 3145728;            // 1024*1024
  unsigned short* Qws = woutT + 1048576;              // 64*2048*64
  unsigned short* Kws = Qws + 8388608;
  unsigned short* Vws = Kws + 8388608;
  unsigned short* Vtws = Vws + 8388608;               // 64*64*2048 (V transposed)
  unsigned short* attn = xbf;                         // alias: xbf dead after gemm_qkv
  // total ws use: 92,274,688 bytes (unchanged)

  cast_x_kernel<<<2097152 / 256, 256, 0, stream>>>(x, xbf, 2097152);
  transpose_cast_kernel<<<dim3(96, 32), dim3(32, 8), 0, stream>>>(Wqkv, wqkvT, 1024, 3072);
  transpose_cast_kernel<<<dim3(32, 32), dim3(32, 8), 0, stream>>>(Wout, woutT, 1024, 1024);
  gemm_qkv_kernel<<<dim3(24, 64), 256, 0, stream>>>(xbf, wqkvT, bqkv, Qws, Kws, Vws);
  transpose_v_kernel<<<dim3(64, 2, 64), dim3(32, 8), 0, stream>>>(Vws, Vtws);
  attn_kernel<<<1024, 256, 0, stream>>>(Qws, Kws, Vtws, attn);
  gemm_out_kernel<<<dim3(8, 64), 256, 0, stream>>>(attn, woutT, bout, out);
}